// Round 7
// baseline (2512.836 us; speedup 1.0000x reference)
//
#include <hip/hip_runtime.h>

#define B_SZ   256
#define T_SZ   1000
#define N_IN   128
#define UNITS  512
#define NC     64        // rows cached in LDS (prefix j<64); row NC = zero row

// dynamic LDS layout (floats/ints at 4B):
//   [0, 133120)        float lds_w[65][512]  (Wz rows 0..63 + zero row 64)
//   [133120, 135552)   int   list[608]       (512 + 96 pad slots of idx 512)
//   [135552, 135584)   int   s_cnt[8]
//   [135584, 135588)   int   s_total
#define SMEM_BYTES 135616

// ---------------------------------------------------------------------------
// Phase 0: Wz[513][512]: W_rec with diag zeroed + all-zero row 512. Pad-slot
// (idx 512) and diagonal gathers return exact +0.0f -> unconditional add
// chain stays bit-identical to the predicated r1 chain (proven r5/r6).
// ---------------------------------------------------------------------------
__global__ __launch_bounds__(512) void wz_prep(const float* __restrict__ Wr,
                                               float* __restrict__ Wz) {
    const int c = threadIdx.x, r = blockIdx.x;
    Wz[(size_t)r * UNITS + c] =
        (r >= UNITS || r == c) ? 0.0f : Wr[(size_t)r * UNITS + c];
}

// ---------------------------------------------------------------------------
// Phase 1: C[M,512] = X[M,128] @ W[128,512]  (unchanged, ~fp32 roofline)
// ---------------------------------------------------------------------------
__global__ __launch_bounds__(256) void gemm_in(const float* __restrict__ X,
                                               const float* __restrict__ W,
                                               float* __restrict__ C) {
    __shared__ __align__(16) float As[32][128];
    __shared__ __align__(16) float Bs[32][128];

    const int tid = threadIdx.x;
    const int ntile = blockIdx.x & 3;
    const int mtile = blockIdx.x >> 2;
    const int m0 = mtile * 128, n0 = ntile * 128;
    const int tm  = (tid >> 4) * 8;
    const int tn4 = (tid & 15) * 4;

    float acc[8][8];
#pragma unroll
    for (int i = 0; i < 8; ++i)
#pragma unroll
        for (int j = 0; j < 8; ++j) acc[i][j] = 0.0f;

    for (int k0 = 0; k0 < 128; k0 += 32) {
        __syncthreads();
#pragma unroll
        for (int r = 0; r < 4; ++r) {
            int li  = r * 256 + tid;
            int row = li >> 3;
            int ch  = li & 7;
            float4 a = *(const float4*)&X[(size_t)(m0 + row) * 128 + k0 + ch * 4];
            As[ch * 4 + 0][row] = a.x;
            As[ch * 4 + 1][row] = a.y;
            As[ch * 4 + 2][row] = a.z;
            As[ch * 4 + 3][row] = a.w;
        }
#pragma unroll
        for (int r = 0; r < 4; ++r) {
            int li = r * 256 + tid;
            int kk = li >> 5;
            int n4 = li & 31;
            *(float4*)&Bs[kk][n4 * 4] =
                *(const float4*)&W[(size_t)(k0 + kk) * 512 + n0 + n4 * 4];
        }
        __syncthreads();

#pragma unroll 8
        for (int k = 0; k < 32; ++k) {
            float4 a0 = *(const float4*)&As[k][tm];
            float4 a1 = *(const float4*)&As[k][tm + 4];
            float4 b0 = *(const float4*)&Bs[k][tn4];
            float4 b1 = *(const float4*)&Bs[k][tn4 + 64];
            const float av[8] = {a0.x, a0.y, a0.z, a0.w, a1.x, a1.y, a1.z, a1.w};
            const float bv[8] = {b0.x, b0.y, b0.z, b0.w, b1.x, b1.y, b1.z, b1.w};
#pragma unroll
            for (int i = 0; i < 8; ++i)
#pragma unroll
                for (int j = 0; j < 8; ++j)
                    acc[i][j] = fmaf(av[i], bv[j], acc[i][j]);
        }
    }

#pragma unroll
    for (int i = 0; i < 8; ++i) {
        size_t row = (size_t)(m0 + tm + i) * 512;
        float4 c0 = make_float4(acc[i][0], acc[i][1], acc[i][2], acc[i][3]);
        float4 c1 = make_float4(acc[i][4], acc[i][5], acc[i][6], acc[i][7]);
        *(float4*)&C[row + n0 + tn4]      = c0;
        *(float4*)&C[row + n0 + 64 + tn4] = c1;
    }
}

// ---------------------------------------------------------------------------
// Phase 2: ALIF scan. One WG per batch (grid 256, 512 thr), thread u owns
// unit u. MLP-bound fix: depth-4 ping-pong gather pipeline (4 static chunk
// buffers, WAR-pinned, no rotation movs) -> 32 global loads in flight per
// wave; plus NC=64 LDS row-cache serving the ascending PREFIX of the active
// list (entries [0, s_cnt[0]) are exactly the actives with j<64) on the
// independent LDS path, hidden under the global prologue latency.
// Accumulation: single acc, strictly ascending j, pads/diag = exact +0.0f
// (bit-identical to the passing r1/r5/r6 chains).
// ---------------------------------------------------------------------------
__global__ __launch_bounds__(512, 2) void alif_scan(const float* __restrict__ Wz,
                                                    float* __restrict__ IO) {
    extern __shared__ __align__(16) float smem[];
    float* lds_w   = smem;                          // [65][512]
    int*   lst     = (int*)(smem + (NC + 1) * UNITS); // [608]
    int*   s_cnt   = lst + 608;                     // [8]
    int*   s_total = s_cnt + 8;                     // [1]

    const int b = blockIdx.x;
    const int u = threadIdx.x;
    const int w = u >> 6;
    const int lane = u & 63;

    const float DECAY   = 0.95122942450071400910f;   // exp(-1/20)
    const float OMD     = 1.0f - DECAY;
    const float DECAY_B = 0.99501247919268232342f;   // exp(-1/200)
    const float OMDB    = 1.0f - DECAY_B;

    float v = 0.0f, ad = 0.0f, z = 0.0f;

    const float* wz = Wz + u;                         // column u of Wz
    float* io = IO + (size_t)b * (T_SZ * UNITS) + u;

    // ---- init: stage LDS weight cache (rows 0..63 of Wz + zero row), pads --
    for (int idx = u; idx < (NC + 1) * UNITS; idx += 512) {
        int row = idx >> 9;
        lds_w[idx] = (row < NC) ? Wz[idx] : 0.0f;
    }
    lst[u] = UNITS;
    if (u < 96) lst[UNITS + u] = UNITS;
    if (u < 8) s_cnt[u] = 0;
    if (u == 0) *s_total = 0;
    __syncthreads();

    float i_cur = io[0];

    // chunk helpers: 8 scalar ds_read idx + 8 gathers into a static buffer
#define LOADCHUNK(G, pos) do {                                     \
        int _a = lst[(pos) + 0], _b = lst[(pos) + 1];              \
        int _c = lst[(pos) + 2], _d = lst[(pos) + 3];              \
        int _e = lst[(pos) + 4], _f = lst[(pos) + 5];              \
        int _g = lst[(pos) + 6], _h = lst[(pos) + 7];              \
        G[0] = wz[_a * UNITS]; G[1] = wz[_b * UNITS];              \
        G[2] = wz[_c * UNITS]; G[3] = wz[_d * UNITS];              \
        G[4] = wz[_e * UNITS]; G[5] = wz[_f * UNITS];              \
        G[6] = wz[_g * UNITS]; G[7] = wz[_h * UNITS];              \
    } while (0)
#define ADDCHUNK(G) do {                                           \
        acc = __fadd_rn(acc, G[0]); acc = __fadd_rn(acc, G[1]);    \
        acc = __fadd_rn(acc, G[2]); acc = __fadd_rn(acc, G[3]);    \
        acc = __fadd_rn(acc, G[4]); acc = __fadd_rn(acc, G[5]);    \
        acc = __fadd_rn(acc, G[6]); acc = __fadd_rn(acc, G[7]);    \
    } while (0)

    for (int t = 0; t < T_SZ; ++t) {
        float i_next = io[(t + 1 < T_SZ ? t + 1 : t) * UNITS];

        const int cnt = *s_total;
        const int c0  = s_cnt[0];          // actives with j < NC (prefix)
        const int k0  = c0;
        const int M   = ((cnt - c0) + 31) & ~31;   // suffix, rounded to 32

        float acc = 0.0f;
        float Ag[8], Bg[8], Cg[8], Dg[8];

        // ---- prologue: 32 global gathers in flight ----
        LOADCHUNK(Ag, k0 + 0);
        LOADCHUNK(Bg, k0 + 8);
        LOADCHUNK(Cg, k0 + 16);
        LOADCHUNK(Dg, k0 + 24);

        // ---- LDS prefix (j<NC actives), hidden under global latency ----
        for (int k = 0; k < c0; k += 8) {
            int j0 = lst[k + 0], j1 = lst[k + 1], j2 = lst[k + 2], j3 = lst[k + 3];
            int j4 = lst[k + 4], j5 = lst[k + 5], j6 = lst[k + 6], j7 = lst[k + 7];
            // entries >= c0 may be j>=NC: clamp to the zero row (in-range)
            j0 = min(j0, NC); j1 = min(j1, NC); j2 = min(j2, NC); j3 = min(j3, NC);
            j4 = min(j4, NC); j5 = min(j5, NC); j6 = min(j6, NC); j7 = min(j7, NC);
            float g0 = lds_w[j0 * UNITS + u], g1 = lds_w[j1 * UNITS + u];
            float g2 = lds_w[j2 * UNITS + u], g3 = lds_w[j3 * UNITS + u];
            float g4 = lds_w[j4 * UNITS + u], g5 = lds_w[j5 * UNITS + u];
            float g6 = lds_w[j6 * UNITS + u], g7 = lds_w[j7 * UNITS + u];
            acc = __fadd_rn(acc, (k + 0 < c0) ? g0 : 0.0f);
            acc = __fadd_rn(acc, (k + 1 < c0) ? g1 : 0.0f);
            acc = __fadd_rn(acc, (k + 2 < c0) ? g2 : 0.0f);
            acc = __fadd_rn(acc, (k + 3 < c0) ? g3 : 0.0f);
            acc = __fadd_rn(acc, (k + 4 < c0) ? g4 : 0.0f);
            acc = __fadd_rn(acc, (k + 5 < c0) ? g5 : 0.0f);
            acc = __fadd_rn(acc, (k + 6 < c0) ? g6 : 0.0f);
            acc = __fadd_rn(acc, (k + 7 < c0) ? g7 : 0.0f);
        }

        // ---- steady depth-4 ping-pong: add chunk k, refill it for k+4 ----
        for (int j = 0; j < M; j += 32) {
            ADDCHUNK(Ag); LOADCHUNK(Ag, k0 + j + 32);
            ADDCHUNK(Bg); LOADCHUNK(Bg, k0 + j + 40);
            ADDCHUNK(Cg); LOADCHUNK(Cg, k0 + j + 48);
            ADDCHUNK(Dg); LOADCHUNK(Dg, k0 + j + 56);
        }

        // ---- elementwise state update — exact reference op order ----
        float newb = __fadd_rn(__fmul_rn(DECAY_B, ad), __fmul_rn(OMDB, z));
        float thr  = __fadd_rn(0.01f, __fmul_rn(newb, 1.6f));
        float it   = __fadd_rn(__fadd_rn(i_cur, acc), 0.0f);       // + ADD_CUR
        float ires = __fmul_rn(__fmul_rn(z, thr), 1.0f);           // * DT
        float newv = __fsub_rn(
            __fadd_rn(__fmul_rn(DECAY, v), __fmul_rn(OMD, it)), ires);
        float zn = (newv > thr) ? 1.0f : 0.0f;      // refractory is a no-op

        io[t * UNITS] = zn;
        v = newv; ad = newb; z = zn; i_cur = i_next;

        // ---- rebuild contiguous ascending active list ----
        unsigned long long m = __ballot(zn > 0.0f);
        if (lane == 0) s_cnt[w] = __popcll(m);
        __syncthreads();   // [A] reads of old list done; counts visible

        int base = 0, total = 0;
#pragma unroll
        for (int i = 0; i < 8; ++i) {
            int c = s_cnt[i];
            total += c;
            if (i < w) base += c;
        }
        if (zn > 0.0f) {
            int pos = base + __popcll(m & ((1ull << lane) - 1ull));
            lst[pos] = u;
        }
        if (u == 0) *s_total = total;
        if (u < 96) lst[total + u] = UNITS;          // pad idx -> zero row
        __syncthreads();   // [C] list ready
    }
#undef LOADCHUNK
#undef ADDCHUNK
}

extern "C" void kernel_launch(void* const* d_in, const int* in_sizes, int n_in,
                              void* d_out, int out_size, void* d_ws, size_t ws_size,
                              hipStream_t stream) {
    (void)in_sizes; (void)n_in; (void)out_size; (void)ws_size;
    const float* x     = (const float*)d_in[0];   // [B,T,128]
    const float* W_in  = (const float*)d_in[1];   // [128,512]
    const float* W_rec = (const float*)d_in[2];   // [512,512]
    float* out = (float*)d_out;                   // [B,T,512]
    float* Wz  = (float*)d_ws;                    // [513][512] zero-diag copy

    wz_prep<<<dim3(UNITS + 1), dim3(UNITS), 0, stream>>>(W_rec, Wz);
    gemm_in<<<dim3((B_SZ * T_SZ / 128) * (UNITS / 128)), dim3(256), 0, stream>>>(
        x, W_in, out);

    hipFuncSetAttribute((const void*)alif_scan,
                        hipFuncAttributeMaxDynamicSharedMemorySize, SMEM_BYTES);
    alif_scan<<<dim3(B_SZ), dim3(512), SMEM_BYTES, stream>>>(Wz, out);
}

// Round 8
// 2097.889 us; speedup vs baseline: 1.1978x; 1.1978x over previous
//
#include <hip/hip_runtime.h>

#define B_SZ   256
#define T_SZ   1000
#define N_IN   128
#define UNITS  512

// ---------------------------------------------------------------------------
// Phase 0: Wz[513][512]: W_rec with diag zeroed + all-zero row 512. Pad-slot
// (idx 512) and diagonal gathers return exact +0.0f -> unconditional add
// chain stays bit-identical to the predicated r1 chain (proven r5/r6/r7).
// ---------------------------------------------------------------------------
__global__ __launch_bounds__(512) void wz_prep(const float* __restrict__ Wr,
                                               float* __restrict__ Wz) {
    const int c = threadIdx.x, r = blockIdx.x;
    Wz[(size_t)r * UNITS + c] =
        (r >= UNITS || r == c) ? 0.0f : Wr[(size_t)r * UNITS + c];
}

// ---------------------------------------------------------------------------
// Phase 1: C[M,512] = X[M,128] @ W[128,512]  (unchanged, ~fp32 roofline)
// ---------------------------------------------------------------------------
__global__ __launch_bounds__(256) void gemm_in(const float* __restrict__ X,
                                               const float* __restrict__ W,
                                               float* __restrict__ C) {
    __shared__ __align__(16) float As[32][128];
    __shared__ __align__(16) float Bs[32][128];

    const int tid = threadIdx.x;
    const int ntile = blockIdx.x & 3;
    const int mtile = blockIdx.x >> 2;
    const int m0 = mtile * 128, n0 = ntile * 128;
    const int tm  = (tid >> 4) * 8;
    const int tn4 = (tid & 15) * 4;

    float acc[8][8];
#pragma unroll
    for (int i = 0; i < 8; ++i)
#pragma unroll
        for (int j = 0; j < 8; ++j) acc[i][j] = 0.0f;

    for (int k0 = 0; k0 < 128; k0 += 32) {
        __syncthreads();
#pragma unroll
        for (int r = 0; r < 4; ++r) {
            int li  = r * 256 + tid;
            int row = li >> 3;
            int ch  = li & 7;
            float4 a = *(const float4*)&X[(size_t)(m0 + row) * 128 + k0 + ch * 4];
            As[ch * 4 + 0][row] = a.x;
            As[ch * 4 + 1][row] = a.y;
            As[ch * 4 + 2][row] = a.z;
            As[ch * 4 + 3][row] = a.w;
        }
#pragma unroll
        for (int r = 0; r < 4; ++r) {
            int li = r * 256 + tid;
            int kk = li >> 5;
            int n4 = li & 31;
            *(float4*)&Bs[kk][n4 * 4] =
                *(const float4*)&W[(size_t)(k0 + kk) * 512 + n0 + n4 * 4];
        }
        __syncthreads();

#pragma unroll 8
        for (int k = 0; k < 32; ++k) {
            float4 a0 = *(const float4*)&As[k][tm];
            float4 a1 = *(const float4*)&As[k][tm + 4];
            float4 b0 = *(const float4*)&Bs[k][tn4];
            float4 b1 = *(const float4*)&Bs[k][tn4 + 64];
            const float av[8] = {a0.x, a0.y, a0.z, a0.w, a1.x, a1.y, a1.z, a1.w};
            const float bv[8] = {b0.x, b0.y, b0.z, b0.w, b1.x, b1.y, b1.z, b1.w};
#pragma unroll
            for (int i = 0; i < 8; ++i)
#pragma unroll
                for (int j = 0; j < 8; ++j)
                    acc[i][j] = fmaf(av[i], bv[j], acc[i][j]);
        }
    }

#pragma unroll
    for (int i = 0; i < 8; ++i) {
        size_t row = (size_t)(m0 + tm + i) * 512;
        float4 c0 = make_float4(acc[i][0], acc[i][1], acc[i][2], acc[i][3]);
        float4 c1 = make_float4(acc[i][4], acc[i][5], acc[i][6], acc[i][7]);
        *(float4*)&C[row + n0 + tn4]      = c0;
        *(float4*)&C[row + n0 + 64 + tn4] = c1;
    }
}

// ---------------------------------------------------------------------------
// Phase 2: ALIF scan. One WG per batch (grid 256, 512 thr), thread u owns
// unit u. The gather is INLINE ASM with counted vmcnt (the compiler has
// collapsed every HIP-level pipeline r2/r5/r7): per 64-slot window, 8 asm
// blocks issue 8 global_load_dword each (64 in flight, early-clobber VGPRs),
// then 8 asm blocks do s_waitcnt vmcnt(56..0) + 8 chained v_add_f32 — the
// SAME instruction and SAME ascending-slot order as all passing rounds;
// pads (idx 512) and diagonal read exact +0.0f from Wz. Extra compiler-
// scheduled loads/stores between blocks only make the waits more
// conservative (vmcnt waits for the N-oldest), never unsafe.
// ---------------------------------------------------------------------------
__global__ __launch_bounds__(512, 2) void alif_scan(const float* __restrict__ Wz,
                                                    float* __restrict__ IO) {
    const int b = blockIdx.x;
    const int u = threadIdx.x;
    const int w = u >> 6;
    const int lane = u & 63;
    const int u4 = u * 4;

    __shared__ __align__(16) int s_list[UNITS + 64];   // 512 + 64 pad
    __shared__ int s_cnt[8];
    __shared__ int s_total;

    const float DECAY   = 0.95122942450071400910f;   // exp(-1/20)
    const float OMD     = 1.0f - DECAY;
    const float DECAY_B = 0.99501247919268232342f;   // exp(-1/200)
    const float OMDB    = 1.0f - DECAY_B;

    float v = 0.0f, ad = 0.0f, z = 0.0f;

    float* io = IO + (size_t)b * (T_SZ * UNITS) + u;

    s_list[u] = UNITS;
    if (u < 64) s_list[UNITS + u] = UNITS;
    if (u == 0) s_total = 0;
    __syncthreads();

    float i_cur = io[0];

// issue 8 independent gathers into early-clobber VGPRs (no waits)
#define LOAD8(p)                                                            \
    asm volatile(                                                           \
        "global_load_dword %0, %8,  %16\n\t"                                \
        "global_load_dword %1, %9,  %16\n\t"                                \
        "global_load_dword %2, %10, %16\n\t"                                \
        "global_load_dword %3, %11, %16\n\t"                                \
        "global_load_dword %4, %12, %16\n\t"                                \
        "global_load_dword %5, %13, %16\n\t"                                \
        "global_load_dword %6, %14, %16\n\t"                                \
        "global_load_dword %7, %15, %16\n\t"                                \
        : "=&v"(G[(p) + 0]), "=&v"(G[(p) + 1]), "=&v"(G[(p) + 2]),          \
          "=&v"(G[(p) + 3]), "=&v"(G[(p) + 4]), "=&v"(G[(p) + 5]),          \
          "=&v"(G[(p) + 6]), "=&v"(G[(p) + 7])                              \
        : "v"(off[(p) + 0]), "v"(off[(p) + 1]), "v"(off[(p) + 2]),          \
          "v"(off[(p) + 3]), "v"(off[(p) + 4]), "v"(off[(p) + 5]),          \
          "v"(off[(p) + 6]), "v"(off[(p) + 7]),                             \
          "s"(Wz))

// wait until the 8 loads of window p are the oldest completed, then add
#define ADD8(p, ncnt)                                                       \
    asm volatile(                                                           \
        "s_waitcnt vmcnt(" #ncnt ")\n\t"                                    \
        "v_add_f32 %0, %0, %1\n\t"                                          \
        "v_add_f32 %0, %0, %2\n\t"                                          \
        "v_add_f32 %0, %0, %3\n\t"                                          \
        "v_add_f32 %0, %0, %4\n\t"                                          \
        "v_add_f32 %0, %0, %5\n\t"                                          \
        "v_add_f32 %0, %0, %6\n\t"                                          \
        "v_add_f32 %0, %0, %7\n\t"                                          \
        "v_add_f32 %0, %0, %8\n\t"                                          \
        : "+v"(acc)                                                         \
        : "v"(G[(p) + 0]), "v"(G[(p) + 1]), "v"(G[(p) + 2]),                \
          "v"(G[(p) + 3]), "v"(G[(p) + 4]), "v"(G[(p) + 5]),                \
          "v"(G[(p) + 6]), "v"(G[(p) + 7]))

    for (int t = 0; t < T_SZ; ++t) {
        float i_next = io[(t + 1 < T_SZ ? t + 1 : t) * UNITS];

        const int cnt = s_total;
        float acc = 0.0f;

        for (int k0 = 0; k0 < cnt; k0 += 64) {
            int4 J[16];
#pragma unroll
            for (int r = 0; r < 16; ++r)
                J[r] = *(const int4*)(s_list + k0 + 4 * r);
            int off[64];
#pragma unroll
            for (int r = 0; r < 16; ++r) {
                off[4 * r + 0] = (J[r].x << 11) + u4;
                off[4 * r + 1] = (J[r].y << 11) + u4;
                off[4 * r + 2] = (J[r].z << 11) + u4;
                off[4 * r + 3] = (J[r].w << 11) + u4;
            }
            float G[64];
            LOAD8(0);  LOAD8(8);  LOAD8(16); LOAD8(24);
            LOAD8(32); LOAD8(40); LOAD8(48); LOAD8(56);
            ADD8(0, 56);  ADD8(8, 48);  ADD8(16, 40); ADD8(24, 32);
            ADD8(32, 24); ADD8(40, 16); ADD8(48, 8);  ADD8(56, 0);
        }

        // ---- elementwise state update — exact reference op order ----
        float newb = __fadd_rn(__fmul_rn(DECAY_B, ad), __fmul_rn(OMDB, z));
        float thr  = __fadd_rn(0.01f, __fmul_rn(newb, 1.6f));
        float it   = __fadd_rn(__fadd_rn(i_cur, acc), 0.0f);       // + ADD_CUR
        float ires = __fmul_rn(__fmul_rn(z, thr), 1.0f);           // * DT
        float newv = __fsub_rn(
            __fadd_rn(__fmul_rn(DECAY, v), __fmul_rn(OMD, it)), ires);
        float zn = (newv > thr) ? 1.0f : 0.0f;      // refractory is a no-op

        io[t * UNITS] = zn;
        v = newv; ad = newb; z = zn; i_cur = i_next;

        // ---- rebuild contiguous ascending active list (r1 scheme) ----
        unsigned long long m = __ballot(zn > 0.0f);
        if (lane == 0) s_cnt[w] = __popcll(m);
        __syncthreads();   // [A] reads of old list done; counts visible

        int base = 0, total = 0;
#pragma unroll
        for (int i = 0; i < 8; ++i) {
            int c = s_cnt[i];
            total += c;
            if (i < w) base += c;
        }
        if (zn > 0.0f) {
            int pos = base + __popcll(m & ((1ull << lane) - 1ull));
            s_list[pos] = u;
        }
        if (u == 0) s_total = total;
        if (u < 64) s_list[total + u] = UNITS;       // pad idx -> zero row
        __syncthreads();   // [C] list ready
    }
#undef LOAD8
#undef ADD8
}

extern "C" void kernel_launch(void* const* d_in, const int* in_sizes, int n_in,
                              void* d_out, int out_size, void* d_ws, size_t ws_size,
                              hipStream_t stream) {
    (void)in_sizes; (void)n_in; (void)out_size; (void)ws_size;
    const float* x     = (const float*)d_in[0];   // [B,T,128]
    const float* W_in  = (const float*)d_in[1];   // [128,512]
    const float* W_rec = (const float*)d_in[2];   // [512,512]
    float* out = (float*)d_out;                   // [B,T,512]
    float* Wz  = (float*)d_ws;                    // [513][512] zero-diag copy

    wz_prep<<<dim3(UNITS + 1), dim3(UNITS), 0, stream>>>(W_rec, Wz);
    gemm_in<<<dim3((B_SZ * T_SZ / 128) * (UNITS / 128)), dim3(256), 0, stream>>>(
        x, W_in, out);
    alif_scan<<<dim3(B_SZ), dim3(512), 0, stream>>>(Wz, out);
}

// Round 9
// 1995.756 us; speedup vs baseline: 1.2591x; 1.0512x over previous
//
#include <hip/hip_runtime.h>

#define B_SZ   256
#define T_SZ   1000
#define N_IN   128
#define UNITS  512
#define NC     64        // rows of Wz cached in LDS; cache row NC = zero row

// dynamic LDS layout (4B words):
//   [0, 33280)      float lds_w[65][512]   (Wz rows 0..63 + zero row 64)
//   [33280, 33808)  int   list[528]        (512 + 16 pad slots of idx 512)
//   [33808, 33816)  int   s_cnt[8]
//   [33816, 33817)  int   s_total
#define SMEM_WORDS (33280 + 528 + 8 + 4)
#define SMEM_BYTES (SMEM_WORDS * 4)

// ---------------------------------------------------------------------------
// Phase 0: Wz[513][512]: W_rec with diag zeroed + all-zero row 512. Pad-slot
// (idx 512) and diagonal gathers return exact +0.0f -> unconditional add
// chain stays bit-identical to the predicated r1 chain (proven r5..r8).
// ---------------------------------------------------------------------------
__global__ __launch_bounds__(512) void wz_prep(const float* __restrict__ Wr,
                                               float* __restrict__ Wz) {
    const int c = threadIdx.x, r = blockIdx.x;
    Wz[(size_t)r * UNITS + c] =
        (r >= UNITS || r == c) ? 0.0f : Wr[(size_t)r * UNITS + c];
}

// ---------------------------------------------------------------------------
// Phase 1: C[M,512] = X[M,128] @ W[128,512]  (unchanged, ~fp32 roofline)
// ---------------------------------------------------------------------------
__global__ __launch_bounds__(256) void gemm_in(const float* __restrict__ X,
                                               const float* __restrict__ W,
                                               float* __restrict__ C) {
    __shared__ __align__(16) float As[32][128];
    __shared__ __align__(16) float Bs[32][128];

    const int tid = threadIdx.x;
    const int ntile = blockIdx.x & 3;
    const int mtile = blockIdx.x >> 2;
    const int m0 = mtile * 128, n0 = ntile * 128;
    const int tm  = (tid >> 4) * 8;
    const int tn4 = (tid & 15) * 4;

    float acc[8][8];
#pragma unroll
    for (int i = 0; i < 8; ++i)
#pragma unroll
        for (int j = 0; j < 8; ++j) acc[i][j] = 0.0f;

    for (int k0 = 0; k0 < 128; k0 += 32) {
        __syncthreads();
#pragma unroll
        for (int r = 0; r < 4; ++r) {
            int li  = r * 256 + tid;
            int row = li >> 3;
            int ch  = li & 7;
            float4 a = *(const float4*)&X[(size_t)(m0 + row) * 128 + k0 + ch * 4];
            As[ch * 4 + 0][row] = a.x;
            As[ch * 4 + 1][row] = a.y;
            As[ch * 4 + 2][row] = a.z;
            As[ch * 4 + 3][row] = a.w;
        }
#pragma unroll
        for (int r = 0; r < 4; ++r) {
            int li = r * 256 + tid;
            int kk = li >> 5;
            int n4 = li & 31;
            *(float4*)&Bs[kk][n4 * 4] =
                *(const float4*)&W[(size_t)(k0 + kk) * 512 + n0 + n4 * 4];
        }
        __syncthreads();

#pragma unroll 8
        for (int k = 0; k < 32; ++k) {
            float4 a0 = *(const float4*)&As[k][tm];
            float4 a1 = *(const float4*)&As[k][tm + 4];
            float4 b0 = *(const float4*)&Bs[k][tn4];
            float4 b1 = *(const float4*)&Bs[k][tn4 + 64];
            const float av[8] = {a0.x, a0.y, a0.z, a0.w, a1.x, a1.y, a1.z, a1.w};
            const float bv[8] = {b0.x, b0.y, b0.z, b0.w, b1.x, b1.y, b1.z, b1.w};
#pragma unroll
            for (int i = 0; i < 8; ++i)
#pragma unroll
                for (int j = 0; j < 8; ++j)
                    acc[i][j] = fmaf(av[i], bv[j], acc[i][j]);
        }
    }

#pragma unroll
    for (int i = 0; i < 8; ++i) {
        size_t row = (size_t)(m0 + tm + i) * 512;
        float4 c0 = make_float4(acc[i][0], acc[i][1], acc[i][2], acc[i][3]);
        float4 c1 = make_float4(acc[i][4], acc[i][5], acc[i][6], acc[i][7]);
        *(float4*)&C[row + n0 + tn4]      = c0;
        *(float4*)&C[row + n0 + 64 + tn4] = c1;
    }
}

// ---------------------------------------------------------------------------
// Phase 2: ALIF scan. One WG per batch (grid 256, 512 thr), thread u owns
// unit u. The scan is L2-BW-bound (r1/r6/r8 all converge at 27-29 TB/s), so
// this round CUTS TRAFFIC: rows 0..63 of Wz are LDS-resident; because the
// active list is ascending, actives with j<64 are exactly list[0..s_cnt[0])
// — a prefix served from LDS (12.5% L2 cut), then the suffix runs r1's
// untouched 8-in-flight global loop.
// Numerics: single acc, globally ascending j. Prefix tail-overrun entries
// clamp to the LDS zero row (+0.0f); the suffix's first group substitutes
// the Wz zero row for pre-c0 slots (+0.0f); trailing pads (idx 512) hit the
// Wz zero row — all bit-identical to the passing r1/r5-r8 chains.
// ---------------------------------------------------------------------------
__global__ __launch_bounds__(512, 2) void alif_scan(const float* __restrict__ Wz,
                                                    float* __restrict__ IO) {
    extern __shared__ __align__(16) float smem[];
    float* lds_w   = smem;                            // [65][512]
    int*   lst     = (int*)(smem + (NC + 1) * UNITS); // [528]
    int*   s_cnt   = lst + 528;                       // [8]
    int*   s_total = s_cnt + 8;                       // [1]

    const int b = blockIdx.x;
    const int u = threadIdx.x;
    const int w = u >> 6;
    const int lane = u & 63;

    const float DECAY   = 0.95122942450071400910f;   // exp(-1/20)
    const float OMD     = 1.0f - DECAY;
    const float DECAY_B = 0.99501247919268232342f;   // exp(-1/200)
    const float OMDB    = 1.0f - DECAY_B;

    float v = 0.0f, ad = 0.0f, z = 0.0f;

    const float* wz = Wz + u;                         // column u of Wz
    float* io = IO + (size_t)b * (T_SZ * UNITS) + u;

    // ---- one-time init: stage LDS cache (Wz rows 0..63 + zero row 64) ----
    for (int idx = u; idx < (NC + 1) * UNITS; idx += 512) {
        lds_w[idx] = (idx < NC * UNITS) ? Wz[idx] : 0.0f;
    }
    lst[u] = UNITS;
    if (u < 16) lst[UNITS + u] = UNITS;
    if (u < 8) s_cnt[u] = 0;
    if (u == 0) *s_total = 0;
    __syncthreads();

    float i_cur = io[0];

    for (int t = 0; t < T_SZ; ++t) {
        // prefetch next step's input current
        float i_next = io[(t + 1 < T_SZ ? t + 1 : t) * UNITS];

        const int cnt = *s_total;
        const int c0  = s_cnt[0];          // actives with j < 64 (list prefix)
        float acc = 0.0f;

        // ---- prefix from LDS cache (zero L2 traffic) ----
        for (int k = 0; k < c0; k += 8) {
            int4 Ja = *(const int4*)(lst + k);
            int4 Jb = *(const int4*)(lst + k + 4);
            // tail overrun (suffix j>=64 or pads) clamps to zero row NC
            int j0 = min(Ja.x, NC), j1 = min(Ja.y, NC);
            int j2 = min(Ja.z, NC), j3 = min(Ja.w, NC);
            int j4 = min(Jb.x, NC), j5 = min(Jb.y, NC);
            int j6 = min(Jb.z, NC), j7 = min(Jb.w, NC);
            float g0 = lds_w[j0 * UNITS + u], g1 = lds_w[j1 * UNITS + u];
            float g2 = lds_w[j2 * UNITS + u], g3 = lds_w[j3 * UNITS + u];
            float g4 = lds_w[j4 * UNITS + u], g5 = lds_w[j5 * UNITS + u];
            float g6 = lds_w[j6 * UNITS + u], g7 = lds_w[j7 * UNITS + u];
            acc = __fadd_rn(acc, g0);
            acc = __fadd_rn(acc, g1);
            acc = __fadd_rn(acc, g2);
            acc = __fadd_rn(acc, g3);
            acc = __fadd_rn(acc, g4);
            acc = __fadd_rn(acc, g5);
            acc = __fadd_rn(acc, g6);
            acc = __fadd_rn(acc, g7);
        }

        // ---- suffix from L2: r1's proven 8-in-flight loop ----
        // starts 8-aligned below c0; pre-c0 slots read the Wz zero row
        for (int k = c0 & ~7; k < cnt; k += 8) {
            int4 Ja = *(const int4*)(lst + k);
            int4 Jb = *(const int4*)(lst + k + 4);
            int j0 = (k + 0 >= c0) ? Ja.x : UNITS;
            int j1 = (k + 1 >= c0) ? Ja.y : UNITS;
            int j2 = (k + 2 >= c0) ? Ja.z : UNITS;
            int j3 = (k + 3 >= c0) ? Ja.w : UNITS;
            int j4 = (k + 4 >= c0) ? Jb.x : UNITS;
            int j5 = (k + 5 >= c0) ? Jb.y : UNITS;
            int j6 = (k + 6 >= c0) ? Jb.z : UNITS;
            int j7 = (k + 7 >= c0) ? Jb.w : UNITS;
            float g0 = wz[j0 * UNITS], g1 = wz[j1 * UNITS];
            float g2 = wz[j2 * UNITS], g3 = wz[j3 * UNITS];
            float g4 = wz[j4 * UNITS], g5 = wz[j5 * UNITS];
            float g6 = wz[j6 * UNITS], g7 = wz[j7 * UNITS];
            acc = __fadd_rn(acc, g0);
            acc = __fadd_rn(acc, g1);
            acc = __fadd_rn(acc, g2);
            acc = __fadd_rn(acc, g3);
            acc = __fadd_rn(acc, g4);
            acc = __fadd_rn(acc, g5);
            acc = __fadd_rn(acc, g6);
            acc = __fadd_rn(acc, g7);
        }

        // ---- elementwise state update — exact reference op order ----
        float newb = __fadd_rn(__fmul_rn(DECAY_B, ad), __fmul_rn(OMDB, z));
        float thr  = __fadd_rn(0.01f, __fmul_rn(newb, 1.6f));
        float it   = __fadd_rn(__fadd_rn(i_cur, acc), 0.0f);       // + ADD_CUR
        float ires = __fmul_rn(__fmul_rn(z, thr), 1.0f);           // * DT
        float newv = __fsub_rn(
            __fadd_rn(__fmul_rn(DECAY, v), __fmul_rn(OMD, it)), ires);
        float zn = (newv > thr) ? 1.0f : 0.0f;      // refractory is a no-op

        io[t * UNITS] = zn;
        v = newv; ad = newb; z = zn; i_cur = i_next;

        // ---- rebuild contiguous ascending active list (r1 scheme) ----
        unsigned long long m = __ballot(zn > 0.0f);
        if (lane == 0) s_cnt[w] = __popcll(m);
        __syncthreads();   // [A] reads of old list done; counts visible

        int base = 0, total = 0;
#pragma unroll
        for (int i = 0; i < 8; ++i) {
            int c = s_cnt[i];
            total += c;
            if (i < w) base += c;
        }
        if (zn > 0.0f) {
            int pos = base + __popcll(m & ((1ull << lane) - 1ull));
            lst[pos] = u;
        }
        if (u == 0) *s_total = total;
        if (u < 16) lst[total + u] = UNITS;          // pad idx -> zero row
        __syncthreads();   // [C] list ready
    }
}

extern "C" void kernel_launch(void* const* d_in, const int* in_sizes, int n_in,
                              void* d_out, int out_size, void* d_ws, size_t ws_size,
                              hipStream_t stream) {
    (void)in_sizes; (void)n_in; (void)out_size; (void)ws_size;
    const float* x     = (const float*)d_in[0];   // [B,T,128]
    const float* W_in  = (const float*)d_in[1];   // [128,512]
    const float* W_rec = (const float*)d_in[2];   // [512,512]
    float* out = (float*)d_out;                   // [B,T,512]
    float* Wz  = (float*)d_ws;                    // [513][512] zero-diag copy

    wz_prep<<<dim3(UNITS + 1), dim3(UNITS), 0, stream>>>(W_rec, Wz);
    gemm_in<<<dim3((B_SZ * T_SZ / 128) * (UNITS / 128)), dim3(256), 0, stream>>>(
        x, W_in, out);

    hipFuncSetAttribute((const void*)alif_scan,
                        hipFuncAttributeMaxDynamicSharedMemorySize, SMEM_BYTES);
    alif_scan<<<dim3(B_SZ), dim3(512), SMEM_BYTES, stream>>>(Wz, out);
}